// Round 4
// baseline (745.619 us; speedup 1.0000x reference)
//
#include <hip/hip_runtime.h>
#include <hip/hip_fp16.h>

#define FEAT   64
#define NNEIGH 6
#define OUTF   64
#define INFEAT (NNEIGH * FEAT)   // 384
#define SPB    64                // sites per block (phase 1)

// ---------------------------------------------------------------------------
// Phase 1: Y[s, k*64 + o] = sum_f X[s, f] * W[o*384 + k*64 + f]
//
// Block = 384 threads = 6 waves. wave = k (0..5), lane = o.
// W[o][k*64 + 0..63] stationary in 16 float4 VGPRs per lane.
// X row address is wave-uniform -> compiler emits s_load (scalar pipe),
// inner loop is v_fmac v_acc, s_x, v_w.
// Store: Y[s][k*64 + lane] -> contiguous 256 B per wave, fully coalesced.
// ---------------------------------------------------------------------------
__global__ __launch_bounds__(384) void lcnn_phase1(
    const float* __restrict__ X, const float* __restrict__ W,
    float* __restrict__ Y, int nsites) {
  const int lane = threadIdx.x & 63;
  const int k    = __builtin_amdgcn_readfirstlane(threadIdx.x >> 6);  // 0..5
  const int base = blockIdx.x * SPB;

  // Stationary W fragment: W4[o*96 + k*16 + i], i = 0..15
  float4 w[16];
  const float4* wp = (const float4*)W + (size_t)lane * (INFEAT / 4) + k * (FEAT / 4);
#pragma unroll
  for (int i = 0; i < 16; ++i) w[i] = wp[i];

  if (base + SPB <= nsites) {
    // full block: fixed trip count, unroll 2 so next site's scalar loads
    // issue under the current site's FMA chain
#pragma unroll 2
    for (int s = 0; s < SPB; ++s) {
      const float4* xr = (const float4*)(X + (size_t)(base + s) * FEAT);
      float acc = 0.f;
#pragma unroll
      for (int i = 0; i < 16; ++i) {
        float4 xv = xr[i];   // uniform address -> scalar load
        acc += xv.x * w[i].x + xv.y * w[i].y + xv.z * w[i].z + xv.w * w[i].w;
      }
      Y[(size_t)(base + s) * INFEAT + k * FEAT + lane] = acc;
    }
  } else {
    const int smax = nsites - base;
    for (int s = 0; s < smax; ++s) {
      const float4* xr = (const float4*)(X + (size_t)(base + s) * FEAT);
      float acc = 0.f;
#pragma unroll
      for (int i = 0; i < 16; ++i) {
        float4 xv = xr[i];
        acc += xv.x * w[i].x + xv.y * w[i].y + xv.z * w[i].z + xv.w * w[i].w;
      }
      Y[(size_t)(base + s) * INFEAT + k * FEAT + lane] = acc;
    }
  }
}

// ---------------------------------------------------------------------------
// Phase 2: out[r, o] = b[o] + sum_k Y[idx[r,k]*384 + k*64 + o]
// One wave per row; lane = o. Row forced uniform -> idx via scalar loads.
// 6 independent coalesced 256 B gathers kept in flight (ILP).
// ---------------------------------------------------------------------------
__global__ __launch_bounds__(256) void lcnn_phase2(
    const int* __restrict__ idx, const float* __restrict__ Y,
    const float* __restrict__ b, float* __restrict__ out, int nrows) {
  const int lane = threadIdx.x & 63;
  int row = blockIdx.x * 4 + (threadIdx.x >> 6);
  if (row >= nrows) return;
  row = __builtin_amdgcn_readfirstlane(row);

  const int* ip = idx + (size_t)row * NNEIGH;
  const int s0 = ip[0], s1 = ip[1], s2 = ip[2], s3 = ip[3], s4 = ip[4], s5 = ip[5];

  const float bb = b[lane];
  const float y0 = Y[(size_t)s0 * INFEAT + 0 * FEAT + lane];
  const float y1 = Y[(size_t)s1 * INFEAT + 1 * FEAT + lane];
  const float y2 = Y[(size_t)s2 * INFEAT + 2 * FEAT + lane];
  const float y3 = Y[(size_t)s3 * INFEAT + 3 * FEAT + lane];
  const float y4 = Y[(size_t)s4 * INFEAT + 4 * FEAT + lane];
  const float y5 = Y[(size_t)s5 * INFEAT + 5 * FEAT + lane];

  out[(size_t)row * OUTF + lane] = bb + ((y0 + y1) + (y2 + y3)) + (y4 + y5);
}

// ---------------------------------------------------------------------------
// Fallback (ws too small): direct 6x-FLOP computation, still correct.
// ---------------------------------------------------------------------------
__global__ __launch_bounds__(256) void lcnn_naive(
    const float* __restrict__ X, const int* __restrict__ idx,
    const float* __restrict__ W, const float* __restrict__ b,
    float* __restrict__ out, int nrows) {
  const int lane = threadIdx.x & 63;
  int row = blockIdx.x * 4 + (threadIdx.x >> 6);
  if (row >= nrows) return;

  const int* ip = idx + (size_t)row * NNEIGH;
  float acc = b[lane];
#pragma unroll 1
  for (int k = 0; k < NNEIGH; ++k) {
    const int s = ip[k];
    const float* xr = X + (size_t)s * FEAT;
    const float* wr = W + (size_t)lane * INFEAT + k * FEAT;
#pragma unroll
    for (int f = 0; f < FEAT; ++f) acc += xr[f] * wr[f];
  }
  out[(size_t)row * OUTF + lane] = acc;
}

extern "C" void kernel_launch(void* const* d_in, const int* in_sizes, int n_in,
                              void* d_out, int out_size, void* d_ws, size_t ws_size,
                              hipStream_t stream) {
  const float* X   = (const float*)d_in[0];
  const int*   idx = (const int*)d_in[1];
  // d_in[2] = N_sites scalar (unused)
  const float* W   = (const float*)d_in[3];
  const float* b   = (const float*)d_in[4];
  float*       out = (float*)d_out;

  const int nsites = in_sizes[0] / FEAT;      // 100000
  const int nrows  = in_sizes[1] / NNEIGH;    // 600000

  const size_t need = (size_t)nsites * INFEAT * sizeof(float);  // 153.6 MB
  if (ws_size >= need) {
    float* Y = (float*)d_ws;
    lcnn_phase1<<<(nsites + SPB - 1) / SPB, 384, 0, stream>>>(X, W, Y, nsites);
    lcnn_phase2<<<(nrows + 3) / 4, 256, 0, stream>>>(idx, Y, b, out, nrows);
  } else {
    lcnn_naive<<<(nrows + 3) / 4, 256, 0, stream>>>(X, idx, W, b, out, nrows);
  }
}

// Round 5
// 511.184 us; speedup vs baseline: 1.4586x; 1.4586x over previous
//
#include <hip/hip_runtime.h>
#include <hip/hip_fp16.h>

#define FEAT   64
#define NNEIGH 6
#define OUTF   64
#define INFEAT (NNEIGH * FEAT)   // 384
#define T1     64                // sites per block (phase 1)

// ---------------------------------------------------------------------------
// Phase 1: Y[s, k*64 + o] = (half) sum_f X[s, f] * W[o*384 + k*64 + f]
//
// Block = 384 threads = 6 waves. wave = k (0..5), lane = o.
// W[o][k*64 .. k*64+63] stationary in 16 float4 VGPRs per lane.
// X tile (64 sites x 64 feat = 16 KB) staged in LDS once per block;
// inner loop reads X via broadcast ds_read_b128 (all lanes same addr,
// conflict-free) -> no scalar-pipe serialization (r3/r4 failure mode).
// Store: Y[s][k*64+lane] fp16 -> contiguous 128 B per wave, coalesced.
// ---------------------------------------------------------------------------
__global__ __launch_bounds__(384) void lcnn_phase1(
    const float* __restrict__ X, const float* __restrict__ W,
    __half* __restrict__ Y, int nsites) {
  __shared__ float xt[T1 * FEAT];          // 16 KB

  const int lane = threadIdx.x & 63;
  const int k    = __builtin_amdgcn_readfirstlane(threadIdx.x >> 6);  // 0..5
  const int base = blockIdx.x * T1;
  const int cnt  = min(T1, nsites - base);

  // Stationary W fragment: 64 floats per lane.
  float4 w[16];
  const float4* wp = (const float4*)W + (size_t)lane * (INFEAT / 4) + k * (FEAT / 4);
#pragma unroll
  for (int i = 0; i < 16; ++i) w[i] = wp[i];

  // Cooperative coalesced load of the X tile into LDS.
  {
    const float4* xg = (const float4*)(X + (size_t)base * FEAT);
    float4* xl = (float4*)xt;
    for (int i = threadIdx.x; i < cnt * (FEAT / 4); i += 384) xl[i] = xg[i];
  }
  __syncthreads();

#pragma unroll 2
  for (int s = 0; s < cnt; ++s) {
    const float4* xr = (const float4*)(xt + s * FEAT);
    float a0 = 0.f, a1 = 0.f, a2 = 0.f, a3 = 0.f;
#pragma unroll
    for (int i = 0; i < 16; i += 4) {
      float4 x0 = xr[i + 0], x1 = xr[i + 1], x2 = xr[i + 2], x3 = xr[i + 3];
      a0 += x0.x * w[i + 0].x + x0.y * w[i + 0].y + x0.z * w[i + 0].z + x0.w * w[i + 0].w;
      a1 += x1.x * w[i + 1].x + x1.y * w[i + 1].y + x1.z * w[i + 1].z + x1.w * w[i + 1].w;
      a2 += x2.x * w[i + 2].x + x2.y * w[i + 2].y + x2.z * w[i + 2].z + x2.w * w[i + 2].w;
      a3 += x3.x * w[i + 3].x + x3.y * w[i + 3].y + x3.z * w[i + 3].z + x3.w * w[i + 3].w;
    }
    const float acc = (a0 + a1) + (a2 + a3);
    Y[(size_t)(base + s) * INFEAT + k * FEAT + lane] = __float2half(acc);
  }
}

// ---------------------------------------------------------------------------
// Phase 2: out[r, o] = b[o] + sum_k Y[idx[r,k]*384 + k*64 + o]
// One wave per row; lane = o. Row uniform -> idx via scalar loads.
// 6 independent fp16 gathers (128 B coalesced each) kept in flight.
// Nontemporal fp32 store: keep the 153.6 MB out-stream from evicting Y in L3.
// ---------------------------------------------------------------------------
__global__ __launch_bounds__(256) void lcnn_phase2(
    const int* __restrict__ idx, const __half* __restrict__ Y,
    const float* __restrict__ b, float* __restrict__ out, int nrows) {
  const int lane = threadIdx.x & 63;
  int row = blockIdx.x * 4 + (threadIdx.x >> 6);
  if (row >= nrows) return;
  row = __builtin_amdgcn_readfirstlane(row);

  const int* ip = idx + (size_t)row * NNEIGH;
  const int s0 = ip[0], s1 = ip[1], s2 = ip[2], s3 = ip[3], s4 = ip[4], s5 = ip[5];

  const __half y0 = Y[(size_t)s0 * INFEAT + 0 * FEAT + lane];
  const __half y1 = Y[(size_t)s1 * INFEAT + 1 * FEAT + lane];
  const __half y2 = Y[(size_t)s2 * INFEAT + 2 * FEAT + lane];
  const __half y3 = Y[(size_t)s3 * INFEAT + 3 * FEAT + lane];
  const __half y4 = Y[(size_t)s4 * INFEAT + 4 * FEAT + lane];
  const __half y5 = Y[(size_t)s5 * INFEAT + 5 * FEAT + lane];

  const float acc = b[lane]
      + ((__half2float(y0) + __half2float(y1)) + (__half2float(y2) + __half2float(y3)))
      + (__half2float(y4) + __half2float(y5));

  __builtin_nontemporal_store(acc, &out[(size_t)row * OUTF + lane]);
}

// ---------------------------------------------------------------------------
// Fallback (ws too small): direct 6x-FLOP computation, still correct.
// ---------------------------------------------------------------------------
__global__ __launch_bounds__(256) void lcnn_naive(
    const float* __restrict__ X, const int* __restrict__ idx,
    const float* __restrict__ W, const float* __restrict__ b,
    float* __restrict__ out, int nrows) {
  const int lane = threadIdx.x & 63;
  int row = blockIdx.x * 4 + (threadIdx.x >> 6);
  if (row >= nrows) return;

  const int* ip = idx + (size_t)row * NNEIGH;
  float acc = b[lane];
#pragma unroll 1
  for (int k = 0; k < NNEIGH; ++k) {
    const int s = ip[k];
    const float* xr = X + (size_t)s * FEAT;
    const float* wr = W + (size_t)lane * INFEAT + k * FEAT;
#pragma unroll
    for (int f = 0; f < FEAT; ++f) acc += xr[f] * wr[f];
  }
  out[(size_t)row * OUTF + lane] = acc;
}

extern "C" void kernel_launch(void* const* d_in, const int* in_sizes, int n_in,
                              void* d_out, int out_size, void* d_ws, size_t ws_size,
                              hipStream_t stream) {
  const float* X   = (const float*)d_in[0];
  const int*   idx = (const int*)d_in[1];
  // d_in[2] = N_sites scalar (unused)
  const float* W   = (const float*)d_in[3];
  const float* b   = (const float*)d_in[4];
  float*       out = (float*)d_out;

  const int nsites = in_sizes[0] / FEAT;      // 100000
  const int nrows  = in_sizes[1] / NNEIGH;    // 600000

  const size_t need = (size_t)nsites * INFEAT * sizeof(__half);  // 76.8 MB
  if (ws_size >= need) {
    __half* Y = (__half*)d_ws;
    lcnn_phase1<<<(nsites + T1 - 1) / T1, 384, 0, stream>>>(X, W, Y, nsites);
    lcnn_phase2<<<(nrows + 3) / 4, 256, 0, stream>>>(idx, Y, b, out, nrows);
  } else {
    lcnn_naive<<<(nrows + 3) / 4, 256, 0, stream>>>(X, idx, W, b, out, nrows);
  }
}

// Round 6
// 361.284 us; speedup vs baseline: 2.0638x; 1.4149x over previous
//
#include <hip/hip_runtime.h>
#include <hip/hip_fp16.h>

#define FEAT   64
#define NNEIGH 6
#define OUTF   64
#define INFEAT (NNEIGH * FEAT)   // 384

typedef __attribute__((ext_vector_type(8))) short bf16x8;
typedef __attribute__((ext_vector_type(4))) float f32x4;

__device__ __forceinline__ short bf16_hi(float v) {
  return (short)(__float_as_uint(v) >> 16);
}
__device__ __forceinline__ float bf16_rec(float v) {
  return __uint_as_float(__float_as_uint(v) & 0xffff0000u);
}

// ---------------------------------------------------------------------------
// Prep: BT[j][f] = W[j%64][(j/64)*64 + f], split into bf16 hi + lo.
// 24576 elements; BT row j is contiguous over f -> B-fragment loads are 16 B.
// ---------------------------------------------------------------------------
__global__ __launch_bounds__(256) void lcnn_prep(
    const float* __restrict__ W, short* __restrict__ BThi,
    short* __restrict__ BTlo) {
  const int t = blockIdx.x * 256 + threadIdx.x;
  if (t >= INFEAT * FEAT) return;
  const int j = t >> 6, f = t & 63;
  const float v = W[(size_t)(j & 63) * INFEAT + (j >> 6) * 64 + f];
  const short h = bf16_hi(v);
  const float lo = v - bf16_rec(v);
  BThi[t] = h;
  BTlo[t] = bf16_hi(lo);
}

// ---------------------------------------------------------------------------
// Phase 1 (MFMA): Y[s][j] = sum_f X[s][f] * BT[j][f], Y stored fp16.
// Block = 256 thr = 4 waves; each wave owns 16 sites x all 384 outputs.
// mfma_f32_16x16x32_bf16, K=64 in 2 k-steps; split-precision (3 MFMA/step).
// A frag: lane(g=l>>4,c=l&15) holds X[m0+c][ks*32+g*8 .. +7]  (16 B fp32 x2)
// B frag: lane holds BT[j0+c][ks*32+g*8 .. +7]                (16 B bf16x8)
// C frag: row=g*4+reg, col=c  -> staged in LDS, stored coalesced.
// ---------------------------------------------------------------------------
__global__ __launch_bounds__(256) void lcnn_p1_mfma(
    const float* __restrict__ X, const short* __restrict__ BThi,
    const short* __restrict__ BTlo, __half* __restrict__ Y, int nsites) {
  __shared__ alignas(16) __half lds[4][16 * INFEAT];   // 48 KB

  const int lane = threadIdx.x & 63;
  const int wid  = threadIdx.x >> 6;
  const int g    = lane >> 4;     // 0..3 (k-group)
  const int c    = lane & 15;     // row/col within tile
  const int m0   = (blockIdx.x * 4 + wid) * 16;

  // --- A fragments: load 16 fp32, split to bf16 hi/lo --------------------
  int srow = m0 + c;
  if (srow >= nsites) srow = nsites - 1;
  const float* xr = X + (size_t)srow * FEAT;

  float af[2][8];
  *(float4*)&af[0][0] = *(const float4*)(xr + g * 8);
  *(float4*)&af[0][4] = *(const float4*)(xr + g * 8 + 4);
  *(float4*)&af[1][0] = *(const float4*)(xr + 32 + g * 8);
  *(float4*)&af[1][4] = *(const float4*)(xr + 32 + g * 8 + 4);

  bf16x8 ah[2], al[2];
#pragma unroll
  for (int ks = 0; ks < 2; ++ks)
#pragma unroll
    for (int i = 0; i < 8; ++i) {
      const float v = af[ks][i];
      ah[ks][i] = bf16_hi(v);
      al[ks][i] = bf16_hi(v - bf16_rec(v));
    }

  // --- 24 N-tiles of 16 ---------------------------------------------------
#pragma unroll 4
  for (int nt = 0; nt < 24; ++nt) {
    const int jrow = (nt * 16 + c) * 64;
    const bf16x8 bh0 = *(const bf16x8*)(BThi + jrow + g * 8);
    const bf16x8 bh1 = *(const bf16x8*)(BThi + jrow + 32 + g * 8);
    const bf16x8 bl0 = *(const bf16x8*)(BTlo + jrow + g * 8);
    const bf16x8 bl1 = *(const bf16x8*)(BTlo + jrow + 32 + g * 8);

    f32x4 acc = {0.f, 0.f, 0.f, 0.f};
    acc = __builtin_amdgcn_mfma_f32_16x16x32_bf16(ah[0], bh0, acc, 0, 0, 0);
    acc = __builtin_amdgcn_mfma_f32_16x16x32_bf16(al[0], bh0, acc, 0, 0, 0);
    acc = __builtin_amdgcn_mfma_f32_16x16x32_bf16(ah[0], bl0, acc, 0, 0, 0);
    acc = __builtin_amdgcn_mfma_f32_16x16x32_bf16(ah[1], bh1, acc, 0, 0, 0);
    acc = __builtin_amdgcn_mfma_f32_16x16x32_bf16(al[1], bh1, acc, 0, 0, 0);
    acc = __builtin_amdgcn_mfma_f32_16x16x32_bf16(ah[1], bl1, acc, 0, 0, 0);

#pragma unroll
    for (int r = 0; r < 4; ++r)
      lds[wid][(g * 4 + r) * INFEAT + nt * 16 + c] = __float2half(acc[r]);
  }

  // --- coalesced store of this wave's 16x384 fp16 tile --------------------
  const int rows = min(16, nsites - m0);
  if (rows > 0) {
    const int n16 = rows * 48;                       // 16B chunks (384*2B/row)
    const uint4* src = (const uint4*)&lds[wid][0];
    uint4* dst = (uint4*)((char*)Y + (size_t)m0 * (INFEAT * 2));
    for (int t = lane; t < n16; t += 64) dst[t] = src[t];
  }
}

// ---------------------------------------------------------------------------
// Phase 2: out[r, o] = b[o] + sum_k Y[idx[r,k]*384 + k*64 + o]
// One wave per row; lane = o; fp16 gathers (128 B coalesced each).
// ---------------------------------------------------------------------------
__global__ __launch_bounds__(256) void lcnn_phase2(
    const int* __restrict__ idx, const __half* __restrict__ Y,
    const float* __restrict__ b, float* __restrict__ out, int nrows) {
  const int lane = threadIdx.x & 63;
  int row = blockIdx.x * 4 + (threadIdx.x >> 6);
  if (row >= nrows) return;
  row = __builtin_amdgcn_readfirstlane(row);

  const int* ip = idx + (size_t)row * NNEIGH;
  const int s0 = ip[0], s1 = ip[1], s2 = ip[2], s3 = ip[3], s4 = ip[4], s5 = ip[5];

  const __half y0 = Y[(size_t)s0 * INFEAT + 0 * FEAT + lane];
  const __half y1 = Y[(size_t)s1 * INFEAT + 1 * FEAT + lane];
  const __half y2 = Y[(size_t)s2 * INFEAT + 2 * FEAT + lane];
  const __half y3 = Y[(size_t)s3 * INFEAT + 3 * FEAT + lane];
  const __half y4 = Y[(size_t)s4 * INFEAT + 4 * FEAT + lane];
  const __half y5 = Y[(size_t)s5 * INFEAT + 5 * FEAT + lane];

  const float acc = b[lane]
      + ((__half2float(y0) + __half2float(y1)) + (__half2float(y2) + __half2float(y3)))
      + (__half2float(y4) + __half2float(y5));

  __builtin_nontemporal_store(acc, &out[(size_t)row * OUTF + lane]);
}

// ---------------------------------------------------------------------------
// Fallback (ws too small): direct computation.
// ---------------------------------------------------------------------------
__global__ __launch_bounds__(256) void lcnn_naive(
    const float* __restrict__ X, const int* __restrict__ idx,
    const float* __restrict__ W, const float* __restrict__ b,
    float* __restrict__ out, int nrows) {
  const int lane = threadIdx.x & 63;
  int row = blockIdx.x * 4 + (threadIdx.x >> 6);
  if (row >= nrows) return;

  const int* ip = idx + (size_t)row * NNEIGH;
  float acc = b[lane];
#pragma unroll 1
  for (int k = 0; k < NNEIGH; ++k) {
    const int s = ip[k];
    const float* xr = X + (size_t)s * FEAT;
    const float* wr = W + (size_t)lane * INFEAT + k * FEAT;
#pragma unroll
    for (int f = 0; f < FEAT; ++f) acc += xr[f] * wr[f];
  }
  out[(size_t)row * OUTF + lane] = acc;
}

extern "C" void kernel_launch(void* const* d_in, const int* in_sizes, int n_in,
                              void* d_out, int out_size, void* d_ws, size_t ws_size,
                              hipStream_t stream) {
  const float* X   = (const float*)d_in[0];
  const int*   idx = (const int*)d_in[1];
  // d_in[2] = N_sites scalar (unused)
  const float* W   = (const float*)d_in[3];
  const float* b   = (const float*)d_in[4];
  float*       out = (float*)d_out;

  const int nsites = in_sizes[0] / FEAT;      // 100000
  const int nrows  = in_sizes[1] / NNEIGH;    // 600000

  const size_t ybytes  = (size_t)nsites * INFEAT * sizeof(__half);  // 76.8 MB
  const size_t btbytes = (size_t)INFEAT * FEAT * sizeof(short);     // 48 KB
  if (ws_size >= ybytes + 2 * btbytes) {
    __half* Y    = (__half*)d_ws;
    short*  BThi = (short*)((char*)d_ws + ybytes);
    short*  BTlo = BThi + INFEAT * FEAT;

    lcnn_prep<<<(INFEAT * FEAT + 255) / 256, 256, 0, stream>>>(W, BThi, BTlo);
    lcnn_p1_mfma<<<(nsites + 63) / 64, 256, 0, stream>>>(X, BThi, BTlo, Y, nsites);
    lcnn_phase2<<<(nrows + 3) / 4, 256, 0, stream>>>(idx, Y, b, out, nrows);
  } else {
    lcnn_naive<<<(nrows + 3) / 4, 256, 0, stream>>>(X, idx, W, b, out, nrows);
  }
}

// Round 7
// 331.995 us; speedup vs baseline: 2.2459x; 1.0882x over previous
//
#include <hip/hip_runtime.h>
#include <hip/hip_fp16.h>

#define FEAT   64
#define NNEIGH 6
#define OUTF   64
#define INFEAT (NNEIGH * FEAT)   // 384

typedef __attribute__((ext_vector_type(8))) short bf16x8;
typedef __attribute__((ext_vector_type(4))) float f32x4;

__device__ __forceinline__ short bf16_hi(float v) {
  return (short)(__float_as_uint(v) >> 16);
}
__device__ __forceinline__ float bf16_rec(float v) {
  return __uint_as_float(__float_as_uint(v) & 0xffff0000u);
}

// ---------------------------------------------------------------------------
// Prep: BT[j][f] = W[j%64][(j/64)*64 + f], split into bf16 hi + lo.
// ---------------------------------------------------------------------------
__global__ __launch_bounds__(256) void lcnn_prep(
    const float* __restrict__ W, short* __restrict__ BThi,
    short* __restrict__ BTlo) {
  const int t = blockIdx.x * 256 + threadIdx.x;
  if (t >= INFEAT * FEAT) return;
  const int j = t >> 6, f = t & 63;
  const float v = W[(size_t)(j & 63) * INFEAT + (j >> 6) * 64 + f];
  BThi[t] = bf16_hi(v);
  BTlo[t] = bf16_hi(v - bf16_rec(v));
}

// ---------------------------------------------------------------------------
// Phase 1 (MFMA, transposed output): Y[s][j] = sum_f X[s][f] * BT[j][f].
// A-frag = BT rows (m = j), B-frag = X rows (n = site).
// D[m=j][n=s]: lane(g=l>>4, c=l&15) holds rows j = nt*16 + g*4 + 0..3 of
// column s = m0+c  ->  4 consecutive halfs = one 8 B store per nt.
// No LDS, no barrier. L2 combines the 32 B segments (verify via WRITE_SIZE).
// ---------------------------------------------------------------------------
__global__ __launch_bounds__(256) void lcnn_p1_mfma(
    const float* __restrict__ X, const short* __restrict__ BThi,
    const short* __restrict__ BTlo, __half* __restrict__ Y, int nsites) {
  const int lane = threadIdx.x & 63;
  const int wid  = threadIdx.x >> 6;
  const int g    = lane >> 4;     // 0..3 (k-group)
  const int c    = lane & 15;
  const int m0   = (blockIdx.x * 4 + wid) * 16;

  int srow = m0 + c;
  const bool valid = (srow < nsites);
  if (!valid) srow = nsites - 1;
  const float* xr = X + (size_t)srow * FEAT;

  float af[2][8];
  *(float4*)&af[0][0] = *(const float4*)(xr + g * 8);
  *(float4*)&af[0][4] = *(const float4*)(xr + g * 8 + 4);
  *(float4*)&af[1][0] = *(const float4*)(xr + 32 + g * 8);
  *(float4*)&af[1][4] = *(const float4*)(xr + 32 + g * 8 + 4);

  bf16x8 xh[2], xl[2];
#pragma unroll
  for (int ks = 0; ks < 2; ++ks)
#pragma unroll
    for (int i = 0; i < 8; ++i) {
      const float v = af[ks][i];
      xh[ks][i] = bf16_hi(v);
      xl[ks][i] = bf16_hi(v - bf16_rec(v));
    }

#pragma unroll 4
  for (int nt = 0; nt < 24; ++nt) {
    const int jrow = (nt * 16 + c) * 64;
    const bf16x8 bh0 = *(const bf16x8*)(BThi + jrow + g * 8);
    const bf16x8 bh1 = *(const bf16x8*)(BThi + jrow + 32 + g * 8);
    const bf16x8 bl0 = *(const bf16x8*)(BTlo + jrow + g * 8);
    const bf16x8 bl1 = *(const bf16x8*)(BTlo + jrow + 32 + g * 8);

    f32x4 acc = {0.f, 0.f, 0.f, 0.f};
    acc = __builtin_amdgcn_mfma_f32_16x16x32_bf16(bh0, xh[0], acc, 0, 0, 0);
    acc = __builtin_amdgcn_mfma_f32_16x16x32_bf16(bh0, xl[0], acc, 0, 0, 0);
    acc = __builtin_amdgcn_mfma_f32_16x16x32_bf16(bl0, xh[0], acc, 0, 0, 0);
    acc = __builtin_amdgcn_mfma_f32_16x16x32_bf16(bh1, xh[1], acc, 0, 0, 0);
    acc = __builtin_amdgcn_mfma_f32_16x16x32_bf16(bh1, xl[1], acc, 0, 0, 0);
    acc = __builtin_amdgcn_mfma_f32_16x16x32_bf16(bl1, xh[1], acc, 0, 0, 0);

    union { __half h[4]; uint2 u; } p;
#pragma unroll
    for (int r = 0; r < 4; ++r) p.h[r] = __float2half(acc[r]);
    if (valid)
      *(uint2*)(Y + (size_t)srow * INFEAT + nt * 16 + g * 4) = p.u;
  }
}

// ---------------------------------------------------------------------------
// Phase 2: out[r, o] = b[o] + sum_k Y[idx[r,k]*384 + k*64 + o]
// Wave handles 8 rows. idx loaded once (lanes 0..47), broadcast via __shfl.
// Gathers are uint (__half2): half-wave per row -> 256 B per instruction,
// 24 independent gathers in flight per wave (6 KB). Stores: 512 B float2.
// ---------------------------------------------------------------------------
__global__ __launch_bounds__(256) void lcnn_phase2(
    const int* __restrict__ idx, const __half* __restrict__ Y,
    const float* __restrict__ b, float* __restrict__ out, int nrows) {
  const int lane = threadIdx.x & 63;
  const int wid  = threadIdx.x >> 6;
  const int l32  = lane & 31;
  const int h    = lane >> 5;
  const int rowbase = (blockIdx.x * 4 + wid) * 8;
  if (rowbase >= nrows) return;

  // lanes 0..47: idx[rowbase*6 + lane]; others clamped (unused).
  const int tmax = nrows * NNEIGH - 1;
  const int iv = idx[min(rowbase * NNEIGH + min(lane, 47), tmax)];

  const float2 bb = *(const float2*)(b + l32 * 2);
  const char* Yb = (const char*)Y;

  uint u[4][6];
#pragma unroll
  for (int rp = 0; rp < 4; ++rp) {
    const int r6 = (rp * 2 + h) * NNEIGH;
#pragma unroll
    for (int k = 0; k < NNEIGH; ++k) {
      const int s = __shfl(iv, r6 + k);
      u[rp][k] = *(const uint*)(Yb + ((size_t)s * (INFEAT * 2) + k * 128 + l32 * 4));
    }
  }

#pragma unroll
  for (int rp = 0; rp < 4; ++rp) {
    float2 a = bb;
#pragma unroll
    for (int k = 0; k < NNEIGH; ++k) {
      const __half2 hh = *(const __half2*)&u[rp][k];
      const float2 f = __half22float2(hh);
      a.x += f.x;
      a.y += f.y;
    }
    const int row = rowbase + rp * 2 + h;
    if (row < nrows)
      *(float2*)(out + (size_t)row * OUTF + l32 * 2) = a;
  }
}

// ---------------------------------------------------------------------------
// Fallback (ws too small): direct computation.
// ---------------------------------------------------------------------------
__global__ __launch_bounds__(256) void lcnn_naive(
    const float* __restrict__ X, const int* __restrict__ idx,
    const float* __restrict__ W, const float* __restrict__ b,
    float* __restrict__ out, int nrows) {
  const int lane = threadIdx.x & 63;
  int row = blockIdx.x * 4 + (threadIdx.x >> 6);
  if (row >= nrows) return;

  const int* ip = idx + (size_t)row * NNEIGH;
  float acc = b[lane];
#pragma unroll 1
  for (int k = 0; k < NNEIGH; ++k) {
    const int s = ip[k];
    const float* xr = X + (size_t)s * FEAT;
    const float* wr = W + (size_t)lane * INFEAT + k * FEAT;
#pragma unroll
    for (int f = 0; f < FEAT; ++f) acc += xr[f] * wr[f];
  }
  out[(size_t)row * OUTF + lane] = acc;
}

extern "C" void kernel_launch(void* const* d_in, const int* in_sizes, int n_in,
                              void* d_out, int out_size, void* d_ws, size_t ws_size,
                              hipStream_t stream) {
  const float* X   = (const float*)d_in[0];
  const int*   idx = (const int*)d_in[1];
  // d_in[2] = N_sites scalar (unused)
  const float* W   = (const float*)d_in[3];
  const float* b   = (const float*)d_in[4];
  float*       out = (float*)d_out;

  const int nsites = in_sizes[0] / FEAT;      // 100000
  const int nrows  = in_sizes[1] / NNEIGH;    // 600000

  const size_t ybytes  = (size_t)nsites * INFEAT * sizeof(__half);  // 76.8 MB
  const size_t btbytes = (size_t)INFEAT * FEAT * sizeof(short);     // 48 KB
  if (ws_size >= ybytes + 2 * btbytes) {
    __half* Y    = (__half*)d_ws;
    short*  BThi = (short*)((char*)d_ws + ybytes);
    short*  BTlo = BThi + INFEAT * FEAT;

    lcnn_prep<<<(INFEAT * FEAT + 255) / 256, 256, 0, stream>>>(W, BThi, BTlo);
    lcnn_p1_mfma<<<(nsites + 63) / 64, 256, 0, stream>>>(X, BThi, BTlo, Y, nsites);
    lcnn_phase2<<<(nrows + 31) / 32, 256, 0, stream>>>(idx, Y, b, out, nrows);
  } else {
    lcnn_naive<<<(nrows + 3) / 4, 256, 0, stream>>>(X, idx, W, b, out, nrows);
  }
}

// Round 9
// 325.394 us; speedup vs baseline: 2.2914x; 1.0203x over previous
//
#include <hip/hip_runtime.h>
#include <hip/hip_fp16.h>

#define FEAT   64
#define NNEIGH 6
#define OUTF   64
#define INFEAT (NNEIGH * FEAT)   // 384

typedef __attribute__((ext_vector_type(8))) short bf16x8;
typedef __attribute__((ext_vector_type(4))) float f32x4;

__device__ __forceinline__ short bf16_hi(float v) {
  return (short)(__float_as_uint(v) >> 16);
}
__device__ __forceinline__ float bf16_rec(float v) {
  return __uint_as_float(__float_as_uint(v) & 0xffff0000u);
}

// ---------------------------------------------------------------------------
// Prep: BT[j][f] = W[j%64][(j/64)*64 + f], split into bf16 hi + lo.
// ---------------------------------------------------------------------------
__global__ __launch_bounds__(256) void lcnn_prep(
    const float* __restrict__ W, short* __restrict__ BThi,
    short* __restrict__ BTlo) {
  const int t = blockIdx.x * 256 + threadIdx.x;
  if (t >= INFEAT * FEAT) return;
  const int j = t >> 6, f = t & 63;
  const float v = W[(size_t)(j & 63) * INFEAT + (j >> 6) * 64 + f];
  BThi[t] = bf16_hi(v);
  BTlo[t] = bf16_hi(v - bf16_rec(v));
}

// ---------------------------------------------------------------------------
// Phase 1 (MFMA, transposed output): Y[s][j] = sum_f X[s][f] * BT[j][f].
// A-frag = BT rows (m = j), B-frag = X rows (n = site).
// D[m=j][n=s]: lane(g=l>>4, c=l&15) holds rows j = nt*16 + g*4 + 0..3 of
// column s = m0+c  ->  4 consecutive halfs = one 8 B store per nt.
// ---------------------------------------------------------------------------
__global__ __launch_bounds__(256) void lcnn_p1_mfma(
    const float* __restrict__ X, const short* __restrict__ BThi,
    const short* __restrict__ BTlo, __half* __restrict__ Y, int nsites) {
  const int lane = threadIdx.x & 63;
  const int wid  = threadIdx.x >> 6;
  const int g    = lane >> 4;     // 0..3 (k-group)
  const int c    = lane & 15;
  const int m0   = (blockIdx.x * 4 + wid) * 16;

  int srow = m0 + c;
  const bool valid = (srow < nsites);
  if (!valid) srow = nsites - 1;
  const float* xr = X + (size_t)srow * FEAT;

  float af[2][8];
  *(float4*)&af[0][0] = *(const float4*)(xr + g * 8);
  *(float4*)&af[0][4] = *(const float4*)(xr + g * 8 + 4);
  *(float4*)&af[1][0] = *(const float4*)(xr + 32 + g * 8);
  *(float4*)&af[1][4] = *(const float4*)(xr + 32 + g * 8 + 4);

  bf16x8 xh[2], xl[2];
#pragma unroll
  for (int ks = 0; ks < 2; ++ks)
#pragma unroll
    for (int i = 0; i < 8; ++i) {
      const float v = af[ks][i];
      xh[ks][i] = bf16_hi(v);
      xl[ks][i] = bf16_hi(v - bf16_rec(v));
    }

#pragma unroll 4
  for (int nt = 0; nt < 24; ++nt) {
    const int jrow = (nt * 16 + c) * 64;
    const bf16x8 bh0 = *(const bf16x8*)(BThi + jrow + g * 8);
    const bf16x8 bh1 = *(const bf16x8*)(BThi + jrow + 32 + g * 8);
    const bf16x8 bl0 = *(const bf16x8*)(BTlo + jrow + g * 8);
    const bf16x8 bl1 = *(const bf16x8*)(BTlo + jrow + 32 + g * 8);

    f32x4 acc = {0.f, 0.f, 0.f, 0.f};
    acc = __builtin_amdgcn_mfma_f32_16x16x32_bf16(bh0, xh[0], acc, 0, 0, 0);
    acc = __builtin_amdgcn_mfma_f32_16x16x32_bf16(bh0, xl[0], acc, 0, 0, 0);
    acc = __builtin_amdgcn_mfma_f32_16x16x32_bf16(bl0, xh[0], acc, 0, 0, 0);
    acc = __builtin_amdgcn_mfma_f32_16x16x32_bf16(bh1, xh[1], acc, 0, 0, 0);
    acc = __builtin_amdgcn_mfma_f32_16x16x32_bf16(bh1, xl[1], acc, 0, 0, 0);
    acc = __builtin_amdgcn_mfma_f32_16x16x32_bf16(bl1, xh[1], acc, 0, 0, 0);

    union { __half h[4]; uint2 u; } p;
#pragma unroll
    for (int r = 0; r < 4; ++r) p.h[r] = __float2half(acc[r]);
    if (valid)
      *(uint2*)(Y + (size_t)srow * INFEAT + nt * 16 + g * 4) = p.u;
  }
}

// ---------------------------------------------------------------------------
// Phase 2: out[r, o] = b[o] + sum_k Y[idx[r,k]*384 + k*64 + o]
// Wave handles 8 rows; idx broadcast via __shfl; 24 outstanding 256 B
// gathers per wave. Stores NONTEMPORAL (no L3 allocate) so the 153.6 MB
// out-stream does not evict the 76.8 MB Y working set (r6: FETCH 233 MB
// vs 91 MB unique -> L3 thrash).
// ---------------------------------------------------------------------------
__global__ __launch_bounds__(256) void lcnn_phase2(
    const int* __restrict__ idx, const __half* __restrict__ Y,
    const float* __restrict__ b, float* __restrict__ out, int nrows) {
  const int lane = threadIdx.x & 63;
  const int wid  = threadIdx.x >> 6;
  const int l32  = lane & 31;
  const int h    = lane >> 5;
  const int rowbase = (blockIdx.x * 4 + wid) * 8;
  if (rowbase >= nrows) return;

  const int tmax = nrows * NNEIGH - 1;
  const int iv = idx[min(rowbase * NNEIGH + min(lane, 47), tmax)];

  const float2 bb = *(const float2*)(b + l32 * 2);
  const char* Yb = (const char*)Y;

  uint u[4][6];
#pragma unroll
  for (int rp = 0; rp < 4; ++rp) {
    const int r6 = (rp * 2 + h) * NNEIGH;
#pragma unroll
    for (int k = 0; k < NNEIGH; ++k) {
      const int s = __shfl(iv, r6 + k);
      u[rp][k] = *(const uint*)(Yb + ((size_t)s * (INFEAT * 2) + k * 128 + l32 * 4));
    }
  }

#pragma unroll
  for (int rp = 0; rp < 4; ++rp) {
    float2 a = bb;
#pragma unroll
    for (int k = 0; k < NNEIGH; ++k) {
      const __half2 hh = *(const __half2*)&u[rp][k];
      const float2 f = __half22float2(hh);
      a.x += f.x;
      a.y += f.y;
    }
    const int row = rowbase + rp * 2 + h;
    if (row < nrows) {
      union { float2 f; double d; } pk;
      pk.f = a;
      __builtin_nontemporal_store(
          pk.d, (double*)(out + (size_t)row * OUTF + l32 * 2));
    }
  }
}

// ---------------------------------------------------------------------------
// Fallback (ws too small): direct computation.
// ---------------------------------------------------------------------------
__global__ __launch_bounds__(256) void lcnn_naive(
    const float* __restrict__ X, const int* __restrict__ idx,
    const float* __restrict__ W, const float* __restrict__ b,
    float* __restrict__ out, int nrows) {
  const int lane = threadIdx.x & 63;
  int row = blockIdx.x * 4 + (threadIdx.x >> 6);
  if (row >= nrows) return;

  const int* ip = idx + (size_t)row * NNEIGH;
  float acc = b[lane];
#pragma unroll 1
  for (int k = 0; k < NNEIGH; ++k) {
    const int s = ip[k];
    const float* xr = X + (size_t)s * FEAT;
    const float* wr = W + (size_t)lane * INFEAT + k * FEAT;
#pragma unroll
    for (int f = 0; f < FEAT; ++f) acc += xr[f] * wr[f];
  }
  out[(size_t)row * OUTF + lane] = acc;
}

extern "C" void kernel_launch(void* const* d_in, const int* in_sizes, int n_in,
                              void* d_out, int out_size, void* d_ws, size_t ws_size,
                              hipStream_t stream) {
  const float* X   = (const float*)d_in[0];
  const int*   idx = (const int*)d_in[1];
  // d_in[2] = N_sites scalar (unused)
  const float* W   = (const float*)d_in[3];
  const float* b   = (const float*)d_in[4];
  float*       out = (float*)d_out;

  const int nsites = in_sizes[0] / FEAT;      // 100000
  const int nrows  = in_sizes[1] / NNEIGH;    // 600000

  const size_t ybytes  = (size_t)nsites * INFEAT * sizeof(__half);  // 76.8 MB
  const size_t btbytes = (size_t)INFEAT * FEAT * sizeof(short);     // 48 KB
  if (ws_size >= ybytes + 2 * btbytes) {
    __half* Y    = (__half*)d_ws;
    short*  BThi = (short*)((char*)d_ws + ybytes);
    short*  BTlo = BThi + INFEAT * FEAT;

    lcnn_prep<<<(INFEAT * FEAT + 255) / 256, 256, 0, stream>>>(W, BThi, BTlo);
    lcnn_p1_mfma<<<(nsites + 63) / 64, 256, 0, stream>>>(X, BThi, BTlo, Y, nsites);
    lcnn_phase2<<<(nrows + 31) / 32, 256, 0, stream>>>(idx, Y, b, out, nrows);
  } else {
    lcnn_naive<<<(nrows + 3) / 4, 256, 0, stream>>>(X, idx, W, b, out, nrows);
  }
}